// Round 1
// baseline (342.847 us; speedup 1.0000x reference)
//
#include <hip/hip_runtime.h>
#include <hip/hip_bf16.h>
#include <cstdint>

#define N_ATOMS 100000
#define NFEAT   256
#define NMOL    1024
#define MP      100096   // 782 * 128, padded rows
#define MTILES  782

static constexpr float SCALE_C = 5.992277830325989f;
static constexpr float SHIFT_C = -406274.63784969115f;

typedef __attribute__((ext_vector_type(8))) short short8;    // bf16x8 MFMA operand
typedef __attribute__((ext_vector_type(4))) float float4_t;  // f32x4 accumulator

__device__ __forceinline__ unsigned short f2bf(float x) {
    union { float f; uint32_t u; } v; v.f = x;
    uint32_t r = (v.u + 0x7fffu + ((v.u >> 16) & 1u)) >> 16;
    return (unsigned short)r;
}

__device__ __forceinline__ float silu(float x) {
    return x / (1.0f + __expf(-x));
}

// async global->LDS, 16B per lane; lds must be wave-uniform (data lands at lds + lane*16)
__device__ __forceinline__ void async16(void* lds, const void* g) {
    __builtin_amdgcn_global_load_lds(
        (const __attribute__((address_space(1))) unsigned int*)(uintptr_t)g,
        (__attribute__((address_space(3))) unsigned int*)(uint32_t)(uintptr_t)lds,
        16, 0, 0);
}

// ---------------------------------------------------------------------------
// Prep: convert atom features fp32 -> bf16 (pad rows [N_ATOMS,MP) with zeros),
// and init out[0..NMOL) = SHIFT (d_out is poisoned before every launch).
// ---------------------------------------------------------------------------
__global__ void prep_convert(const float* __restrict__ A,
                             unsigned short* __restrict__ Abf,
                             float* __restrict__ out) {
    size_t i = (size_t)blockIdx.x * blockDim.x + threadIdx.x;  // one float4 per thread
    size_t base = i * 4;
    if (base < (size_t)MP * NFEAT) {
        ushort4 o;
        if (base < (size_t)N_ATOMS * NFEAT) {
            float4 v = ((const float4*)A)[i];
            o.x = f2bf(v.x); o.y = f2bf(v.y); o.z = f2bf(v.z); o.w = f2bf(v.w);
        } else {
            o.x = 0; o.y = 0; o.z = 0; o.w = 0;
        }
        ((ushort4*)Abf)[i] = o;
    }
    if (i < NMOL) out[i] = SHIFT_C;
}

// ---------------------------------------------------------------------------
// Prep: W1,W2 fp32 [k][n] -> bf16 transposed [n][k] (for contiguous B staging)
// ---------------------------------------------------------------------------
__global__ void prep_weights(const float* __restrict__ W1, const float* __restrict__ W2,
                             unsigned short* __restrict__ W1t, unsigned short* __restrict__ W2t) {
    int g = blockIdx.x * 256 + threadIdx.x;  // 0 .. 2*65536-1
    const float* W = (g < 65536) ? W1 : W2;
    unsigned short* Wt = (g < 65536) ? W1t : W2t;
    int idx = g & 65535;
    int k = idx >> 8, n = idx & 255;
    Wt[n * 256 + k] = f2bf(W[idx]);
}

// ---------------------------------------------------------------------------
// GEMM: C[m][n] = silu(sum_k A[m][k]*W[k][n] + bias[n])
//   MODE 0: store C as bf16 into Hout
//   MODE 1: e = C . W3 (+b3 once) per row; atomicAdd(out[batch[m]], SCALE*e)
// 128x128 tile, BK=32, 256 threads = 4 waves (2x2 of 64x64), mfma 16x16x32 bf16
// ---------------------------------------------------------------------------
template <int MODE>
__global__ __launch_bounds__(256, 2)
void gemm_kernel(const unsigned short* __restrict__ Abf,  // [MP][256] bf16
                 const unsigned short* __restrict__ Wt,   // [256][256] bf16, [n][k]
                 const float* __restrict__ bias,          // [256]
                 unsigned short* __restrict__ Hout,       // MODE 0
                 const float* __restrict__ W3,            // MODE 1
                 const float* __restrict__ b3,            // MODE 1
                 const int* __restrict__ batch,           // MODE 1
                 float* __restrict__ out) {               // MODE 1
    __shared__ unsigned short As[128 * 32];
    __shared__ unsigned short Bs[128 * 32];
    __shared__ float red[128 * 2];

    const int tid  = threadIdx.x;
    const int wv   = tid >> 6;
    const int lane = tid & 63;
    const int m0   = blockIdx.x * 128;
    const int n0   = blockIdx.y * 128;
    const int wm   = (wv >> 1) * 64;   // wave row offset in tile
    const int wn   = (wv & 1) * 64;    // wave col offset in tile
    const int fl   = lane & 15;
    const int qd   = lane >> 4;
    const int srow = lane >> 2;        // staging row within 16-row chunk
    const int scol = (lane & 3) * 8;   // staging k offset (elements)

    float4_t acc[4][4] = {};

    for (int k0 = 0; k0 < 256; k0 += 32) {
#pragma unroll
        for (int i = 0; i < 2; ++i) {
            int r = i * 64 + wv * 16;  // wave-uniform chunk base row
            async16(&As[r * 32], Abf + (size_t)(m0 + r + srow) * 256 + k0 + scol);
            async16(&Bs[r * 32], Wt  + (size_t)(n0 + r + srow) * 256 + k0 + scol);
        }
        __syncthreads();  // compiler emits vmcnt(0) drain before barrier

        short8 af[4], bf[4];
#pragma unroll
        for (int mi = 0; mi < 4; ++mi)
            af[mi] = *(const short8*)&As[(wm + mi * 16 + fl) * 32 + qd * 8];
#pragma unroll
        for (int ni = 0; ni < 4; ++ni)
            bf[ni] = *(const short8*)&Bs[(wn + ni * 16 + fl) * 32 + qd * 8];
#pragma unroll
        for (int mi = 0; mi < 4; ++mi)
#pragma unroll
            for (int ni = 0; ni < 4; ++ni)
                acc[mi][ni] = __builtin_amdgcn_mfma_f32_16x16x32_bf16(
                    af[mi], bf[ni], acc[mi][ni], 0, 0, 0);
        __syncthreads();
    }

    if (MODE == 0) {
#pragma unroll
        for (int ni = 0; ni < 4; ++ni) {
            int col = n0 + wn + ni * 16 + fl;
            float b = bias[col];
#pragma unroll
            for (int mi = 0; mi < 4; ++mi) {
#pragma unroll
                for (int r = 0; r < 4; ++r) {
                    int row = m0 + wm + mi * 16 + qd * 4 + r;
                    float h = silu(acc[mi][ni][r] + b);
                    Hout[(size_t)row * 256 + col] = f2bf(h);
                }
            }
        }
    } else {
        float rs[4][4] = {};  // [mi][r] partial row sums over this wave's 64 cols
#pragma unroll
        for (int ni = 0; ni < 4; ++ni) {
            int col = n0 + wn + ni * 16 + fl;
            float b = bias[col];
            float w3 = W3[col];
#pragma unroll
            for (int mi = 0; mi < 4; ++mi)
#pragma unroll
                for (int r = 0; r < 4; ++r)
                    rs[mi][r] += silu(acc[mi][ni][r] + b) * w3;
        }
        // reduce across the 16 lanes (cols) of each quad
#pragma unroll
        for (int mi = 0; mi < 4; ++mi)
#pragma unroll
            for (int r = 0; r < 4; ++r) {
                float v = rs[mi][r];
                v += __shfl_xor(v, 1);
                v += __shfl_xor(v, 2);
                v += __shfl_xor(v, 4);
                v += __shfl_xor(v, 8);
                rs[mi][r] = v;
            }
        if (fl == 0) {
#pragma unroll
            for (int mi = 0; mi < 4; ++mi)
#pragma unroll
                for (int r = 0; r < 4; ++r)
                    red[(wm + mi * 16 + qd * 4 + r) * 2 + (wv & 1)] = rs[mi][r];
        }
        __syncthreads();
        if (tid < 128) {
            int atom = m0 + tid;
            if (atom < N_ATOMS) {
                float v = red[tid * 2] + red[tid * 2 + 1];
                if (n0 == 0) v += b3[0];
                atomicAdd(&out[batch[atom]], v * SCALE_C);
            }
        }
    }
}

// ---------------------------------------------------------------------------
extern "C" void kernel_launch(void* const* d_in, const int* in_sizes, int n_in,
                              void* d_out, int out_size, void* d_ws, size_t ws_size,
                              hipStream_t stream) {
    const float* A     = (const float*)d_in[0];
    const int*   batch = (const int*)d_in[1];
    const float* W1    = (const float*)d_in[2];
    const float* b1    = (const float*)d_in[3];
    const float* W2    = (const float*)d_in[4];
    const float* b2    = (const float*)d_in[5];
    const float* W3    = (const float*)d_in[6];
    const float* b3    = (const float*)d_in[7];
    float* out = (float*)d_out;

    unsigned short* Abf = (unsigned short*)d_ws;             // MP*256 bf16
    unsigned short* H1  = Abf + (size_t)MP * NFEAT;          // MP*256 bf16
    unsigned short* W1t = H1 + (size_t)MP * NFEAT;           // 256*256 bf16
    unsigned short* W2t = W1t + 256 * 256;

    // prep: A conversion (+ out=SHIFT init), weight transpose+convert
    prep_convert<<<dim3((MP * NFEAT / 4 + 255) / 256), 256, 0, stream>>>(A, Abf, out);
    prep_weights<<<dim3(512), 256, 0, stream>>>(W1, W2, W1t, W2t);

    // layer 1: H1 = silu(A @ W1 + b1)
    gemm_kernel<0><<<dim3(MTILES, 2), 256, 0, stream>>>(
        Abf, W1t, b1, H1, nullptr, nullptr, nullptr, nullptr);
    // layer 2+3+pool: out[mol] += SCALE * (silu(H1@W2+b2) . W3 + b3)
    gemm_kernel<1><<<dim3(MTILES, 2), 256, 0, stream>>>(
        H1, W2t, b2, nullptr, W3, b3, batch, out);
}